// Round 3
// baseline (4180.338 us; speedup 1.0000x reference)
//
#include <hip/hip_runtime.h>
#include <math.h>

// MultiViewAggregation — two-kernel fp32 pipeline.
// Kernel A: PBR MLP, 1 thread = 1 (px,view,sg) instance, scalar (SGPR) weights,
//           32-col chunking with LDS park row to cap VGPR ~112.
// Kernel B: per-pixel transformer, 2 px per 256-thread block, conflict-free strides.

#define NPIX 16384

// ---------------- Kernel A ----------------
#define NTA 192   // 2 px * 8 views * 12 sg = 192 instances
#define NBA (NPIX/2)

__device__ __forceinline__ float elu_f(float x){ return x > 0.f ? x : (__expf(x) - 1.f); }
__device__ __forceinline__ float gelu_f(float x){ return 0.5f*x*(1.f + erff(x*0.70710678118654752f)); }

struct AParams {
  const float* view_dir; const float* normal; const float* DL;
  const float* ln_g; const float* ln_b;
  const float* w1; const float* b1; const float* w2; const float* b2;
  const float* w3; const float* b3; const float* w4; const float* b4;
  float* feat;   // [NPIX*8][32]
};

__global__ __launch_bounds__(NTA, 2)
void mva_phaseA(AParams P)
{
  __shared__ float lds[NTA*33];   // park rows [192][33]; head aliased as fb[6][16][36]=3456
  const int t   = threadIdx.x;
  const int pxv = t & 15;          // px_l(1) | view(3)
  const int sg  = t >> 4;          // 0..11
  const int px  = blockIdx.x*2 + (pxv >> 3);
  const int view = pxv & 7;

  float y[64];
  // ---- inputs + tiny LN ----
  {
    const float* nrm = P.normal + px*3;
    const float nm0 = nrm[0], nm1 = nrm[1], nm2 = nrm[2];
    const float* vd = P.view_dir + (px*8 + view)*3;
    const float vd0 = vd[0], vd1 = vd[1], vd2 = vd[2];
    const float* dl = P.DL + px*84 + sg*7;
    const float d0=dl[0], d1=dl[1], d2=dl[2], d3=dl[3], d4=dl[4], d5=dl[5], d6=dl[6];

    const float DLdotN = d0*nm0 + d1*nm1 + d2*nm2;
    const float hv     = (d0*vd0 + d1*vd1 + d2*vd2 + 1.f)*0.5f;
    const float fres   = exp2f((-5.55472f*hv - 6.98316f)*hv);
    const float VdotN  = vd0*nm0 + vd1*nm1 + vd2*nm2;

    float x[7] = {DLdotN, d3, d4, d5, d6, fres, VdotN};
    float m = (x[0]+x[1]+x[2]+x[3]+x[4]+x[5]+x[6])*(1.f/7.f);
    float var = 0.f;
    #pragma unroll
    for (int k = 0; k < 7; ++k){ float q = x[k]-m; var += q*q; }
    var *= (1.f/7.f);
    const float rs = rsqrtf(var + 1e-5f);
    float xl[7];
    #pragma unroll
    for (int k = 0; k < 7; ++k) xl[k] = (x[k]-m)*rs*P.ln_g[k] + P.ln_b[k];

    // ---- layer 1: 7 -> 64 (elu); scalar weights ----
    #pragma unroll
    for (int c = 0; c < 64; c += 4){
      float a0 = P.b1[c+0], a1 = P.b1[c+1], a2 = P.b1[c+2], a3 = P.b1[c+3];
      #pragma unroll
      for (int k = 0; k < 7; ++k){
        const float* w = P.w1 + k*64 + c;
        const float yk = xl[k];
        a0 = fmaf(yk, w[0], a0); a1 = fmaf(yk, w[1], a1);
        a2 = fmaf(yk, w[2], a2); a3 = fmaf(yk, w[3], a3);
      }
      y[c+0]=elu_f(a0); y[c+1]=elu_f(a1); y[c+2]=elu_f(a2); y[c+3]=elu_f(a3);
    }
  }

  // ---- layers 2,3: 64 -> 64 (elu), chunked (park chunk0 in LDS) ----
  float* park = lds + t*33;
  #pragma unroll 1
  for (int L = 0; L < 2; ++L){
    const float* W = L ? P.w3 : P.w2;
    const float* B = L ? P.b3 : P.b2;
    // chunk 0: cols 0..31 -> park
    #pragma unroll
    for (int c = 0; c < 32; c += 4){
      float a0 = B[c+0], a1 = B[c+1], a2 = B[c+2], a3 = B[c+3];
      #pragma unroll
      for (int k = 0; k < 64; ++k){
        const float* w = W + k*64 + c;
        const float yk = y[k];
        a0 = fmaf(yk, w[0], a0); a1 = fmaf(yk, w[1], a1);
        a2 = fmaf(yk, w[2], a2); a3 = fmaf(yk, w[3], a3);
      }
      park[c+0]=elu_f(a0); park[c+1]=elu_f(a1); park[c+2]=elu_f(a2); park[c+3]=elu_f(a3);
    }
    // chunk 1: cols 32..63 -> regs
    float yn[32];
    #pragma unroll
    for (int c = 0; c < 32; c += 4){
      float a0 = B[32+c+0], a1 = B[32+c+1], a2 = B[32+c+2], a3 = B[32+c+3];
      #pragma unroll
      for (int k = 0; k < 64; ++k){
        const float* w = W + k*64 + 32 + c;
        const float yk = y[k];
        a0 = fmaf(yk, w[0], a0); a1 = fmaf(yk, w[1], a1);
        a2 = fmaf(yk, w[2], a2); a3 = fmaf(yk, w[3], a3);
      }
      yn[c+0]=elu_f(a0); yn[c+1]=elu_f(a1); yn[c+2]=elu_f(a2); yn[c+3]=elu_f(a3);
    }
    #pragma unroll
    for (int j = 0; j < 32; ++j){ y[j] = park[j]; y[32+j] = yn[j]; }
  }

  // ---- layer 4: 64 -> 32 ----
  float f[32];
  #pragma unroll
  for (int c = 0; c < 32; c += 4){
    float a0 = P.b4[c+0], a1 = P.b4[c+1], a2 = P.b4[c+2], a3 = P.b4[c+3];
    #pragma unroll
    for (int k = 0; k < 64; ++k){
      const float* w = P.w4 + k*32 + c;
      const float yk = y[k];
      a0 = fmaf(yk, w[0], a0); a1 = fmaf(yk, w[1], a1);
      a2 = fmaf(yk, w[2], a2); a3 = fmaf(yk, w[3], a3);
    }
    f[c+0]=a0; f[c+1]=a1; f[c+2]=a2; f[c+3]=a3;
  }

  // ---- sg reduction: pair via shfl, 6 partials via LDS, final sum ----
  #pragma unroll
  for (int i = 0; i < 32; ++i) f[i] += __shfl_xor(f[i], 32);

  __syncthreads();   // park rows dead; fb aliases lds[0..3456)
  if ((t & 32) == 0){
    const int pairid = ((t >> 6) << 1) | ((t >> 4) & 1);   // 0..5
    float* fb = lds + pairid*576 + pxv*36;
    #pragma unroll
    for (int i = 0; i < 8; ++i)
      *(float4*)(fb + 4*i) = make_float4(f[4*i], f[4*i+1], f[4*i+2], f[4*i+3]);
  }
  __syncthreads();

  for (int u = t; u < 512; u += NTA){
    const int pv = u >> 5, c = u & 31;
    float s = 0.f;
    #pragma unroll
    for (int p = 0; p < 6; ++p) s += lds[p*576 + pv*36 + c];
    P.feat[(size_t)blockIdx.x*512 + pv*32 + c] = s;
  }
}

// ---------------- Kernel B ----------------
#define NTB 256
#define NBB (NPIX/2)

struct BParams {
  const float* rgb; const float* fm; const float* proj_err; const float* feat;
  const float* tv1_ln_g; const float* tv1_ln_b; const float* tv1_w;
  const float* to1_w; const float* to1_b;
  const float* n1_ln_g; const float* n1_ln_b; const float* n1_w1; const float* n1_b1;
  const float* n1_w2; const float* n1_b2;
  const float* tv2_ln_g; const float* tv2_ln_b; const float* tv2_w;
  const float* to2_w; const float* to2_b;
  const float* n2_ln_g; const float* n2_ln_b; const float* n2_w1; const float* n2_b1;
  const float* n2_w2; const float* n2_b2;
  const float* brdf_ln_g; const float* brdf_ln_b; const float* brdf_w1; const float* brdf_b1;
  const float* brdf_w2; const float* brdf_b2;
  float* out;
};

// LDS layout (floats)
constexpr int XLN   = 0;             // [16][100]
constexpr int HID   = 1600;          // [16][132] (n1 chunks) / [2][260] (per-pixel)
constexpr int XINB  = 3712;          // [16][100]
constexpr int XCUR  = XINB + 1600;   // [16][100]
constexpr int VB    = XCUR + 1600;   // [16][36]
constexpr int MEANB = VB + 576;      // [2][32]
constexpr int VARB  = MEANB + 64;    // [2][32]
constexpr int WGTB  = VARB + 64;     // 16
constexpr int XSB   = WGTB + 16;     // [2][96]
constexpr int XSLNB = XSB + 192;     // [2][96]
constexpr int SMTOT = XSLNB + 192;   // 8016 floats = 32 KB

__device__ __forceinline__ void fma4(float4& a, float s, const float4 w){
  a.x = fmaf(s, w.x, a.x); a.y = fmaf(s, w.y, a.y);
  a.z = fmaf(s, w.z, a.z); a.w = fmaf(s, w.w, a.w);
}

// LN of 16 rows x 96 (t<128, 8 lanes/row), bank-staggered columns.
__device__ __forceinline__ void ln16(const float* __restrict__ in,
                                     float* __restrict__ out,
                                     const float* __restrict__ g, const float* __restrict__ b,
                                     int t)
{
  if (t < 128){
    const int r = t >> 3, l8 = t & 7;
    const float* row = in + r*100;
    float vals[12]; int cols[12];
    float s1 = 0.f, s2 = 0.f;
    #pragma unroll
    for (int i = 0; i < 12; ++i){
      int c = l8 + 8*i + 8*(r & 7); if (c >= 96) c -= 96;
      float a = row[c];
      cols[i] = c; vals[i] = a; s1 += a; s2 += a*a;
    }
    s1 += __shfl_xor(s1, 1); s2 += __shfl_xor(s2, 1);
    s1 += __shfl_xor(s1, 2); s2 += __shfl_xor(s2, 2);
    s1 += __shfl_xor(s1, 4); s2 += __shfl_xor(s2, 4);
    float mean = s1*(1.f/96.f);
    float var  = s2*(1.f/96.f) - mean*mean;
    float rs = rsqrtf(var + 1e-5f);
    float* orow = out + r*100;
    #pragma unroll
    for (int i = 0; i < 12; ++i){
      int c = cols[i];
      orow[c] = (vals[i]-mean)*rs*g[c] + b[c];
    }
  }
}

// LN of 2 rows x 96 (t<32, 16 lanes/row), stride 96.
__device__ __forceinline__ void lnP(const float* __restrict__ in,
                                    float* __restrict__ out,
                                    const float* __restrict__ g, const float* __restrict__ b,
                                    int t)
{
  if (t < 32){
    const int r = t >> 4, l = t & 15;
    const float* row = in + r*96;
    float vals[6];
    float s1 = 0.f, s2 = 0.f;
    #pragma unroll
    for (int i = 0; i < 6; ++i){
      float a = row[l + 16*i];
      vals[i] = a; s1 += a; s2 += a*a;
    }
    s1 += __shfl_xor(s1, 1); s2 += __shfl_xor(s2, 1);
    s1 += __shfl_xor(s1, 2); s2 += __shfl_xor(s2, 2);
    s1 += __shfl_xor(s1, 4); s2 += __shfl_xor(s2, 4);
    s1 += __shfl_xor(s1, 8); s2 += __shfl_xor(s2, 8);
    float mean = s1*(1.f/96.f);
    float var  = s2*(1.f/96.f) - mean*mean;
    float rs = rsqrtf(var + 1e-5f);
    float* orow = out + r*96;
    #pragma unroll
    for (int i = 0; i < 6; ++i){
      int c = l + 16*i;
      orow[c] = (vals[i]-mean)*rs*g[c] + b[c];
    }
  }
}

// 16-row matmul; unit = (c4, row). 16 lanes broadcast-share each weight float4.
template<int K, int C, int LDW, bool GELU, bool HASB, bool RES, bool ACC>
__device__ __forceinline__ void mm16(const float* __restrict__ inb, int S,
                                     const float* __restrict__ Wg, const float* __restrict__ bg,
                                     float* __restrict__ outb, int So,
                                     const float* __restrict__ residb, int t)
{
  constexpr int C4 = C/4;
  const float4* __restrict__ W4 = (const float4*)Wg;
  for (int gi = t; gi < C4*16; gi += NTB){
    const int r = gi & 15, c4 = gi >> 4;
    const float2* x = (const float2*)(inb + r*S);
    float4 a = HASB ? ((const float4*)bg)[c4] : make_float4(0.f,0.f,0.f,0.f);
    #pragma unroll 4
    for (int k2 = 0; k2 < K/2; ++k2){
      float2 xv = x[k2];
      fma4(a, xv.x, W4[(2*k2)*(LDW/4) + c4]);
      fma4(a, xv.y, W4[(2*k2+1)*(LDW/4) + c4]);
    }
    if (GELU){ a.x=gelu_f(a.x); a.y=gelu_f(a.y); a.z=gelu_f(a.z); a.w=gelu_f(a.w); }
    if (RES){
      float4 rr = *(const float4*)(residb + r*100 + 4*c4);
      a.x += rr.x; a.y += rr.y; a.z += rr.z; a.w += rr.w;
    }
    float* o = outb + r*So + 4*c4;
    if (ACC){
      float4 ov = *(const float4*)o;
      a.x += ov.x; a.y += ov.y; a.z += ov.z; a.w += ov.w;
    }
    *(float4*)o = a;
  }
}

// 2-row (per-pixel) matmul, k-split 4; unit = (c, kq). Combine via shfl.
template<int K, int C, int LDW, bool GELU, bool HASB, bool RES>
__device__ __forceinline__ void mmpx(const float* __restrict__ inb, int S,
                                     const float* __restrict__ Wg, const float* __restrict__ bg,
                                     float* __restrict__ outb, int So,
                                     const float* __restrict__ residb, int Sr, int t)
{
  for (int gi = t; gi < 4*C; gi += NTB){
    const int kq = gi & 3, c = gi >> 2;
    const int k0 = kq*(K/4);
    float a0 = 0.f, a1 = 0.f;
    #pragma unroll 4
    for (int kk = 0; kk < K/4; ++kk){
      const float w = Wg[(k0+kk)*LDW + c];
      a0 = fmaf(inb[k0+kk],     w, a0);
      a1 = fmaf(inb[S + k0+kk], w, a1);
    }
    a0 += __shfl_xor(a0, 1); a1 += __shfl_xor(a1, 1);
    a0 += __shfl_xor(a0, 2); a1 += __shfl_xor(a1, 2);
    if (kq == 0){
      if (HASB){ const float b = bg[c]; a0 += b; a1 += b; }
      if (GELU){ a0 = gelu_f(a0); a1 = gelu_f(a1); }
      if (RES){ a0 += residb[c]; a1 += residb[Sr + c]; }
      outb[c] = a0; outb[So + c] = a1;
    }
  }
}

__global__ __launch_bounds__(NTB, 4)
void mva_phaseB(BParams P)
{
  __shared__ __align__(16) float smem[SMTOT];
  const int t = threadIdx.x;
  const int bpx0 = blockIdx.x*2;

  // xin: rgb(3) | fm(61) | feat(32), rows = 16 (2px x 8v), stride 100
  for (int u = t; u < 1024; u += NTB){
    const int r = u >> 6, k = u & 63;
    const int pl = r >> 3, v = r & 7;
    float val = (k < 3) ? P.rgb[((bpx0+pl)*8 + v)*3 + k]
                        : P.fm[(bpx0+pl)*61 + (k-3)];
    smem[XINB + r*100 + k] = val;
  }
  for (int u = t; u < 512; u += NTB){
    const int r = u >> 5, c = u & 31;
    smem[XINB + r*100 + 64 + c] = P.feat[(size_t)blockIdx.x*512 + r*32 + c];
  }
  if (t < 16){
    float pe = P.proj_err[(bpx0 + (t>>3))*8 + (t&7)];
    float wraw = fmaxf(-log10f(fabsf(pe) + 1e-6f), 0.f);
    float s = wraw;
    s += __shfl_xor(s, 1); s += __shfl_xor(s, 2); s += __shfl_xor(s, 4);
    smem[WGTB + t] = wraw / (s + 1e-6f);
  }
  __syncthreads();

  // tv1: v = LN(xin) @ tv1_w
  ln16(smem+XINB, smem+XLN, P.tv1_ln_g, P.tv1_ln_b, t);
  __syncthreads();
  mm16<96,32,32,false,false,false,false>(smem+XLN, 100, P.tv1_w, nullptr, smem+VB, 36, nullptr, t);
  __syncthreads();
  if (t < 64){
    const int pl = t >> 5, c = t & 31;
    const float* wn = smem + WGTB + pl*8;
    float m = 0.f;
    #pragma unroll
    for (int v = 0; v < 8; ++v) m += wn[v]*smem[VB + (pl*8+v)*36 + c];
    float vv = 0.f;
    #pragma unroll
    for (int v = 0; v < 8; ++v){ float d = smem[VB + (pl*8+v)*36 + c] - m; vv += wn[v]*d*d; }
    smem[MEANB + pl*32 + c] = m;
    smem[VARB  + pl*32 + c] = vv;
  }
  __syncthreads();
  // xcat = [v | mean | var] -> XLN
  for (int u = t; u < 1536; u += NTB){
    const int c = u >> 4, r = u & 15;
    const int pl = r >> 3;
    float val = (c < 32) ? smem[VB + r*36 + c]
              : (c < 64) ? smem[MEANB + pl*32 + (c-32)]
                         : smem[VARB + pl*32 + (c-64)];
    smem[XLN + r*100 + c] = val;
  }
  __syncthreads();
  mm16<96,96,96,false,true,true,false>(smem+XLN, 100, P.to1_w, P.to1_b, smem+XCUR, 100, smem+XINB, t);
  __syncthreads();

  // n1 (hidden 256 in two 128 chunks)
  ln16(smem+XCUR, smem+XLN, P.n1_ln_g, P.n1_ln_b, t);
  __syncthreads();
  mm16<96,128,256,true,true,false,false>(smem+XLN, 100, P.n1_w1, P.n1_b1, smem+HID, 132, nullptr, t);
  __syncthreads();
  mm16<128,96,96,false,true,true,false>(smem+HID, 132, P.n1_w2, P.n1_b2, smem+XCUR, 100, smem+XINB, t);
  __syncthreads();
  mm16<96,128,256,true,true,false,false>(smem+XLN, 100, P.n1_w1 + 128, P.n1_b1 + 128, smem+HID, 132, nullptr, t);
  __syncthreads();
  mm16<128,96,96,false,false,false,true>(smem+HID, 132, P.n1_w2 + 128*96, nullptr, smem+XCUR, 100, nullptr, t);
  __syncthreads();

  // tv2 + weighted stats
  ln16(smem+XCUR, smem+XLN, P.tv2_ln_g, P.tv2_ln_b, t);
  __syncthreads();
  mm16<96,32,32,false,false,false,false>(smem+XLN, 100, P.tv2_w, nullptr, smem+VB, 36, nullptr, t);
  __syncthreads();
  if (t < 64){
    const int pl = t >> 5, c = t & 31;
    const float* wn = smem + WGTB + pl*8;
    float m = 0.f;
    #pragma unroll
    for (int v = 0; v < 8; ++v) m += wn[v]*smem[VB + (pl*8+v)*36 + c];
    float vv = 0.f;
    #pragma unroll
    for (int v = 0; v < 8; ++v){ float d = smem[VB + (pl*8+v)*36 + c] - m; vv += wn[v]*d*d; }
    smem[MEANB + pl*32 + c] = m;
    smem[VARB  + pl*32 + c] = vv;
  }
  __syncthreads();
  // xcat2 per pixel: [v[row0] | mean | var] -> XSLNB
  if (t < 192){
    const int pl = t / 96, k = t - pl*96;
    float val = (k < 32) ? smem[VB + (pl*8)*36 + k]
              : (k < 64) ? smem[MEANB + pl*32 + (k-32)]
                         : smem[VARB + pl*32 + (k-64)];
    smem[XSLNB + pl*96 + k] = val;
  }
  __syncthreads();
  mmpx<96,96,96,false,true,true>(smem+XSLNB, 96, P.to2_w, P.to2_b, smem+XSB, 96, smem+XINB, 800, t);
  __syncthreads();

  // n2 (per pixel)
  lnP(smem+XSB, smem+XSLNB, P.n2_ln_g, P.n2_ln_b, t);
  __syncthreads();
  mmpx<96,256,256,true,true,false>(smem+XSLNB, 96, P.n2_w1, P.n2_b1, smem+HID, 260, nullptr, 0, t);
  __syncthreads();
  mmpx<256,96,96,false,true,true>(smem+HID, 260, P.n2_w2, P.n2_b2, smem+XSB, 96, smem+XINB, 800, t);
  __syncthreads();

  // brdf head
  lnP(smem+XSB, smem+XSLNB, P.brdf_ln_g, P.brdf_ln_b, t);
  __syncthreads();
  mmpx<96,128,128,true,true,false>(smem+XSLNB, 96, P.brdf_w1, P.brdf_b1, smem+HID, 260, nullptr, 0, t);
  __syncthreads();
  mmpx<128,128,128,false,true,false>(smem+HID, 260, P.brdf_w2, P.brdf_b2,
                                     P.out + (size_t)bpx0*128, 128, nullptr, 0, t);
}

extern "C" void kernel_launch(void* const* d_in, const int* in_sizes, int n_in,
                              void* d_out, int out_size, void* d_ws, size_t ws_size,
                              hipStream_t stream)
{
  (void)in_sizes; (void)n_in; (void)ws_size; (void)out_size;
  int i = 0;
  const float* rgb      = (const float*)d_in[i++];
  const float* fm       = (const float*)d_in[i++];
  const float* view_dir = (const float*)d_in[i++];
  const float* proj_err = (const float*)d_in[i++];
  const float* normal   = (const float*)d_in[i++];
  const float* DL       = (const float*)d_in[i++];

  AParams A;
  A.view_dir = view_dir; A.normal = normal; A.DL = DL;
  A.ln_g = (const float*)d_in[i++]; A.ln_b = (const float*)d_in[i++];
  A.w1 = (const float*)d_in[i++]; A.b1 = (const float*)d_in[i++];
  A.w2 = (const float*)d_in[i++]; A.b2 = (const float*)d_in[i++];
  A.w3 = (const float*)d_in[i++]; A.b3 = (const float*)d_in[i++];
  A.w4 = (const float*)d_in[i++]; A.b4 = (const float*)d_in[i++];
  A.feat = (float*)d_ws;

  BParams B;
  B.rgb = rgb; B.fm = fm; B.proj_err = proj_err; B.feat = (const float*)d_ws;
  B.tv1_ln_g = (const float*)d_in[i++]; B.tv1_ln_b = (const float*)d_in[i++];
  B.tv1_w = (const float*)d_in[i++];
  B.to1_w = (const float*)d_in[i++]; B.to1_b = (const float*)d_in[i++];
  B.n1_ln_g = (const float*)d_in[i++]; B.n1_ln_b = (const float*)d_in[i++];
  B.n1_w1 = (const float*)d_in[i++]; B.n1_b1 = (const float*)d_in[i++];
  B.n1_w2 = (const float*)d_in[i++]; B.n1_b2 = (const float*)d_in[i++];
  B.tv2_ln_g = (const float*)d_in[i++]; B.tv2_ln_b = (const float*)d_in[i++];
  B.tv2_w = (const float*)d_in[i++];
  B.to2_w = (const float*)d_in[i++]; B.to2_b = (const float*)d_in[i++];
  B.n2_ln_g = (const float*)d_in[i++]; B.n2_ln_b = (const float*)d_in[i++];
  B.n2_w1 = (const float*)d_in[i++]; B.n2_b1 = (const float*)d_in[i++];
  B.n2_w2 = (const float*)d_in[i++]; B.n2_b2 = (const float*)d_in[i++];
  B.brdf_ln_g = (const float*)d_in[i++]; B.brdf_ln_b = (const float*)d_in[i++];
  B.brdf_w1 = (const float*)d_in[i++]; B.brdf_b1 = (const float*)d_in[i++];
  B.brdf_w2 = (const float*)d_in[i++]; B.brdf_b2 = (const float*)d_in[i++];
  B.out = (float*)d_out;

  mva_phaseA<<<dim3(NBA), dim3(NTA), 0, stream>>>(A);
  mva_phaseB<<<dim3(NBB), dim3(NTB), 0, stream>>>(B);
}

// Round 4
// 2005.240 us; speedup vs baseline: 2.0847x; 2.0847x over previous
//
#include <hip/hip_runtime.h>
#include <math.h>

// MultiViewAggregation — two-kernel fp32 pipeline, round 4.
// Kernel A: PBR MLP, 1 thread = 1 (px,view,sg) instance. ALL activations in
//           named float4 registers (no arrays -> no scratch demotion).
//           Weights via uniform global loads (compile-time offsets -> s_load).
// Kernel B: per-pixel transformer (round-3 structure), unroll-8, free occupancy.

#define NPIX 16384

__device__ __forceinline__ float elu_f(float x){ return x > 0.f ? x : (__expf(x) - 1.f); }
__device__ __forceinline__ float gelu_f(float x){ return 0.5f*x*(1.f + erff(x*0.70710678118654752f)); }

// ===================== Kernel A =====================
#define NTA 384          // 4 px * 8 views * 12 sg / ... = 384 instances
#define NBA (NPIX/4)

struct AParams {
  const float* view_dir; const float* normal; const float* DL;
  const float* ln_g; const float* ln_b;
  const float* w1; const float* b1; const float* w2; const float* b2;
  const float* w3; const float* b3; const float* w4; const float* b4;
  float* feat;   // [(px*8+view)][32]
};

#define FMA4(A, S, WV) { float4 _w = (WV); \
  A.x = fmaf((S), _w.x, A.x); A.y = fmaf((S), _w.y, A.y); \
  A.z = fmaf((S), _w.z, A.z); A.w = fmaf((S), _w.w, A.w); }

#define ELU4(A) make_float4(elu_f(A.x), elu_f(A.y), elu_f(A.z), elu_f(A.w))

// accumulate 4 k-steps (one source float4 Sq) into A; W row-stride LD float4s
#define AK4W(A, Sq, W, base, LD) \
  FMA4(A, (Sq).x, W[(base)]) \
  FMA4(A, (Sq).y, W[(base)+(LD)]) \
  FMA4(A, (Sq).z, W[(base)+2*(LD)]) \
  FMA4(A, (Sq).w, W[(base)+3*(LD)])

// one output col-quad cb (64-wide layer, LD=16)
#define COL64(A, W, B4, cb, S) { A = B4[cb]; \
  AK4W(A, S##0,  W,  0*64+(cb), 16) AK4W(A, S##1,  W,  1*64+(cb), 16) \
  AK4W(A, S##2,  W,  2*64+(cb), 16) AK4W(A, S##3,  W,  3*64+(cb), 16) \
  AK4W(A, S##4,  W,  4*64+(cb), 16) AK4W(A, S##5,  W,  5*64+(cb), 16) \
  AK4W(A, S##6,  W,  6*64+(cb), 16) AK4W(A, S##7,  W,  7*64+(cb), 16) \
  AK4W(A, S##8,  W,  8*64+(cb), 16) AK4W(A, S##9,  W,  9*64+(cb), 16) \
  AK4W(A, S##10, W, 10*64+(cb), 16) AK4W(A, S##11, W, 11*64+(cb), 16) \
  AK4W(A, S##12, W, 12*64+(cb), 16) AK4W(A, S##13, W, 13*64+(cb), 16) \
  AK4W(A, S##14, W, 14*64+(cb), 16) AK4W(A, S##15, W, 15*64+(cb), 16) }

// full 64->64 layer with elu: D0..D15 <- S0..S15
#define LAYER64(D, S, W, B4) { float4 _a; \
  COL64(_a, W, B4, 0,  S) D##0  = ELU4(_a); \
  COL64(_a, W, B4, 1,  S) D##1  = ELU4(_a); \
  COL64(_a, W, B4, 2,  S) D##2  = ELU4(_a); \
  COL64(_a, W, B4, 3,  S) D##3  = ELU4(_a); \
  COL64(_a, W, B4, 4,  S) D##4  = ELU4(_a); \
  COL64(_a, W, B4, 5,  S) D##5  = ELU4(_a); \
  COL64(_a, W, B4, 6,  S) D##6  = ELU4(_a); \
  COL64(_a, W, B4, 7,  S) D##7  = ELU4(_a); \
  COL64(_a, W, B4, 8,  S) D##8  = ELU4(_a); \
  COL64(_a, W, B4, 9,  S) D##9  = ELU4(_a); \
  COL64(_a, W, B4, 10, S) D##10 = ELU4(_a); \
  COL64(_a, W, B4, 11, S) D##11 = ELU4(_a); \
  COL64(_a, W, B4, 12, S) D##12 = ELU4(_a); \
  COL64(_a, W, B4, 13, S) D##13 = ELU4(_a); \
  COL64(_a, W, B4, 14, S) D##14 = ELU4(_a); \
  COL64(_a, W, B4, 15, S) D##15 = ELU4(_a); }

// one output col-quad of the 64->32 layer (LD=8), no activation
#define COL32(A, W, B4, cb, S) { A = B4[cb]; \
  AK4W(A, S##0,  W,  0*32+(cb), 8) AK4W(A, S##1,  W,  1*32+(cb), 8) \
  AK4W(A, S##2,  W,  2*32+(cb), 8) AK4W(A, S##3,  W,  3*32+(cb), 8) \
  AK4W(A, S##4,  W,  4*32+(cb), 8) AK4W(A, S##5,  W,  5*32+(cb), 8) \
  AK4W(A, S##6,  W,  6*32+(cb), 8) AK4W(A, S##7,  W,  7*32+(cb), 8) \
  AK4W(A, S##8,  W,  8*32+(cb), 8) AK4W(A, S##9,  W,  9*32+(cb), 8) \
  AK4W(A, S##10, W, 10*32+(cb), 8) AK4W(A, S##11, W, 11*32+(cb), 8) \
  AK4W(A, S##12, W, 12*32+(cb), 8) AK4W(A, S##13, W, 13*32+(cb), 8) \
  AK4W(A, S##14, W, 14*32+(cb), 8) AK4W(A, S##15, W, 15*32+(cb), 8) }

#define COLL1(A, B4, cb) { A = B4[cb]; \
  FMA4(A, xl0, W1v[ 0+(cb)]) FMA4(A, xl1, W1v[16+(cb)]) \
  FMA4(A, xl2, W1v[32+(cb)]) FMA4(A, xl3, W1v[48+(cb)]) \
  FMA4(A, xl4, W1v[64+(cb)]) FMA4(A, xl5, W1v[80+(cb)]) \
  FMA4(A, xl6, W1v[96+(cb)]) }

#define SHF32(A) { A.x += __shfl_xor(A.x, 32); A.y += __shfl_xor(A.y, 32); \
                   A.z += __shfl_xor(A.z, 32); A.w += __shfl_xor(A.w, 32); }

#define ST4(p, o, A) { (p)[(o)] = A.x; (p)[(o)+1] = A.y; (p)[(o)+2] = A.z; (p)[(o)+3] = A.w; }

__global__ __launch_bounds__(NTA)
void mva_phaseA(AParams P)
{
  __shared__ float fb[6*32*33];   // per-wave partials [wave][pxv][33]
  const int t   = threadIdx.x;
  const int pxv = t & 31;          // px_l(2) | view(3)
  const int sg  = t >> 5;          // 0..11 (wave w holds sg {2w,2w+1})
  const int px  = blockIdx.x*4 + (pxv >> 3);
  const int view = pxv & 7;

  // ---- inputs + 7-wide LN (pure registers) ----
  const float nm0 = P.normal[px*3+0], nm1 = P.normal[px*3+1], nm2 = P.normal[px*3+2];
  const float* vd = P.view_dir + (px*8 + view)*3;
  const float vd0 = vd[0], vd1 = vd[1], vd2 = vd[2];
  const float* dl = P.DL + px*84 + sg*7;
  const float d0=dl[0], d1=dl[1], d2=dl[2], d3=dl[3], d4=dl[4], d5=dl[5], d6=dl[6];

  const float DLdotN = d0*nm0 + d1*nm1 + d2*nm2;
  const float hv     = (d0*vd0 + d1*vd1 + d2*vd2 + 1.f)*0.5f;
  const float fres   = exp2f((-5.55472f*hv - 6.98316f)*hv);
  const float VdotN  = vd0*nm0 + vd1*nm1 + vd2*nm2;

  const float x0 = DLdotN, x1 = d3, x2 = d4, x3 = d5, x4 = d6, x5 = fres, x6 = VdotN;
  const float m  = (x0+x1+x2+x3+x4+x5+x6)*(1.f/7.f);
  float q, var = 0.f;
  q = x0-m; var += q*q; q = x1-m; var += q*q; q = x2-m; var += q*q;
  q = x3-m; var += q*q; q = x4-m; var += q*q; q = x5-m; var += q*q;
  q = x6-m; var += q*q;
  const float rs = rsqrtf(var*(1.f/7.f) + 1e-5f);
  const float xl0 = (x0-m)*rs*P.ln_g[0] + P.ln_b[0];
  const float xl1 = (x1-m)*rs*P.ln_g[1] + P.ln_b[1];
  const float xl2 = (x2-m)*rs*P.ln_g[2] + P.ln_b[2];
  const float xl3 = (x3-m)*rs*P.ln_g[3] + P.ln_b[3];
  const float xl4 = (x4-m)*rs*P.ln_g[4] + P.ln_b[4];
  const float xl5 = (x5-m)*rs*P.ln_g[5] + P.ln_b[5];
  const float xl6 = (x6-m)*rs*P.ln_g[6] + P.ln_b[6];

  const float4* __restrict__ W1v = (const float4*)P.w1;
  const float4* __restrict__ B1v = (const float4*)P.b1;
  const float4* __restrict__ W2v = (const float4*)P.w2;
  const float4* __restrict__ B2v = (const float4*)P.b2;
  const float4* __restrict__ W3v = (const float4*)P.w3;
  const float4* __restrict__ B3v = (const float4*)P.b3;
  const float4* __restrict__ W4v = (const float4*)P.w4;
  const float4* __restrict__ B4v = (const float4*)P.b4;

  // ---- layer 1: 7 -> 64 (elu) ----
  float4 Y0,Y1,Y2,Y3,Y4,Y5,Y6,Y7,Y8,Y9,Y10,Y11,Y12,Y13,Y14,Y15;
  { float4 _a;
    COLL1(_a, B1v, 0)  Y0  = ELU4(_a);
    COLL1(_a, B1v, 1)  Y1  = ELU4(_a);
    COLL1(_a, B1v, 2)  Y2  = ELU4(_a);
    COLL1(_a, B1v, 3)  Y3  = ELU4(_a);
    COLL1(_a, B1v, 4)  Y4  = ELU4(_a);
    COLL1(_a, B1v, 5)  Y5  = ELU4(_a);
    COLL1(_a, B1v, 6)  Y6  = ELU4(_a);
    COLL1(_a, B1v, 7)  Y7  = ELU4(_a);
    COLL1(_a, B1v, 8)  Y8  = ELU4(_a);
    COLL1(_a, B1v, 9)  Y9  = ELU4(_a);
    COLL1(_a, B1v, 10) Y10 = ELU4(_a);
    COLL1(_a, B1v, 11) Y11 = ELU4(_a);
    COLL1(_a, B1v, 12) Y12 = ELU4(_a);
    COLL1(_a, B1v, 13) Y13 = ELU4(_a);
    COLL1(_a, B1v, 14) Y14 = ELU4(_a);
    COLL1(_a, B1v, 15) Y15 = ELU4(_a);
  }

  // ---- layer 2: 64 -> 64 (elu) ----
  float4 Z0,Z1,Z2,Z3,Z4,Z5,Z6,Z7,Z8,Z9,Z10,Z11,Z12,Z13,Z14,Z15;
  LAYER64(Z, Y, W2v, B2v)

  // ---- layer 3: 64 -> 64 (elu), back into Y ----
  LAYER64(Y, Z, W3v, B3v)

  // ---- layer 4: 64 -> 32 ----
  float4 F0,F1,F2,F3,F4,F5,F6,F7;
  { float4 _a;
    COL32(_a, W4v, B4v, 0, Y) F0 = _a;
    COL32(_a, W4v, B4v, 1, Y) F1 = _a;
    COL32(_a, W4v, B4v, 2, Y) F2 = _a;
    COL32(_a, W4v, B4v, 3, Y) F3 = _a;
    COL32(_a, W4v, B4v, 4, Y) F4 = _a;
    COL32(_a, W4v, B4v, 5, Y) F5 = _a;
    COL32(_a, W4v, B4v, 6, Y) F6 = _a;
    COL32(_a, W4v, B4v, 7, Y) F7 = _a;
  }

  // ---- sg reduction: partner (sg^1) via shfl, then 6 wave-partials via LDS ----
  SHF32(F0) SHF32(F1) SHF32(F2) SHF32(F3)
  SHF32(F4) SHF32(F5) SHF32(F6) SHF32(F7)

  if ((t & 63) < 32){
    float* row = fb + (t>>6)*1056 + pxv*33;   // stride 33: conflict-free
    ST4(row, 0,  F0) ST4(row, 4,  F1) ST4(row, 8,  F2) ST4(row, 12, F3)
    ST4(row, 16, F4) ST4(row, 20, F5) ST4(row, 24, F6) ST4(row, 28, F7)
  }
  __syncthreads();

  for (int u = t; u < 1024; u += NTA){
    const int pv = u >> 5, c = u & 31;
    float s = 0.f;
    #pragma unroll
    for (int w = 0; w < 6; ++w) s += fb[w*1056 + pv*33 + c];
    P.feat[(size_t)blockIdx.x*1024 + u] = s;
  }
}

// ===================== Kernel B =====================
#define NTB 256
#define NBB (NPIX/2)

struct BParams {
  const float* rgb; const float* fm; const float* proj_err; const float* feat;
  const float* tv1_ln_g; const float* tv1_ln_b; const float* tv1_w;
  const float* to1_w; const float* to1_b;
  const float* n1_ln_g; const float* n1_ln_b; const float* n1_w1; const float* n1_b1;
  const float* n1_w2; const float* n1_b2;
  const float* tv2_ln_g; const float* tv2_ln_b; const float* tv2_w;
  const float* to2_w; const float* to2_b;
  const float* n2_ln_g; const float* n2_ln_b; const float* n2_w1; const float* n2_b1;
  const float* n2_w2; const float* n2_b2;
  const float* brdf_ln_g; const float* brdf_ln_b; const float* brdf_w1; const float* brdf_b1;
  const float* brdf_w2; const float* brdf_b2;
  float* out;
};

constexpr int XLN   = 0;             // [16][100]
constexpr int HID   = 1600;          // [16][132] / [2][260]
constexpr int XINB  = 3712;          // [16][100]
constexpr int XCUR  = XINB + 1600;   // [16][100]
constexpr int VB    = XCUR + 1600;   // [16][36]
constexpr int MEANB = VB + 576;      // [2][32]
constexpr int VARB  = MEANB + 64;    // [2][32]
constexpr int WGTB  = VARB + 64;     // 16
constexpr int XSB   = WGTB + 16;     // [2][96]
constexpr int XSLNB = XSB + 192;     // [2][96]
constexpr int SMTOT = XSLNB + 192;   // 8016 floats = 32 KB

__device__ __forceinline__ void fma4(float4& a, float s, const float4 w){
  a.x = fmaf(s, w.x, a.x); a.y = fmaf(s, w.y, a.y);
  a.z = fmaf(s, w.z, a.z); a.w = fmaf(s, w.w, a.w);
}

__device__ __forceinline__ void ln16(const float* __restrict__ in,
                                     float* __restrict__ out,
                                     const float* __restrict__ g, const float* __restrict__ b,
                                     int t)
{
  if (t < 128){
    const int r = t >> 3, l8 = t & 7;
    const float* row = in + r*100;
    float vals[12]; int cols[12];
    float s1 = 0.f, s2 = 0.f;
    #pragma unroll
    for (int i = 0; i < 12; ++i){
      int c = l8 + 8*i + 8*(r & 7); if (c >= 96) c -= 96;
      float a = row[c];
      cols[i] = c; vals[i] = a; s1 += a; s2 += a*a;
    }
    s1 += __shfl_xor(s1, 1); s2 += __shfl_xor(s2, 1);
    s1 += __shfl_xor(s1, 2); s2 += __shfl_xor(s2, 2);
    s1 += __shfl_xor(s1, 4); s2 += __shfl_xor(s2, 4);
    float mean = s1*(1.f/96.f);
    float var  = s2*(1.f/96.f) - mean*mean;
    float rsd = rsqrtf(var + 1e-5f);
    float* orow = out + r*100;
    #pragma unroll
    for (int i = 0; i < 12; ++i){
      int c = cols[i];
      orow[c] = (vals[i]-mean)*rsd*g[c] + b[c];
    }
  }
}

__device__ __forceinline__ void lnP(const float* __restrict__ in,
                                    float* __restrict__ out,
                                    const float* __restrict__ g, const float* __restrict__ b,
                                    int t)
{
  if (t < 32){
    const int r = t >> 4, l = t & 15;
    const float* row = in + r*96;
    float vals[6];
    float s1 = 0.f, s2 = 0.f;
    #pragma unroll
    for (int i = 0; i < 6; ++i){
      float a = row[l + 16*i];
      vals[i] = a; s1 += a; s2 += a*a;
    }
    s1 += __shfl_xor(s1, 1); s2 += __shfl_xor(s2, 1);
    s1 += __shfl_xor(s1, 2); s2 += __shfl_xor(s2, 2);
    s1 += __shfl_xor(s1, 4); s2 += __shfl_xor(s2, 4);
    s1 += __shfl_xor(s1, 8); s2 += __shfl_xor(s2, 8);
    float mean = s1*(1.f/96.f);
    float var  = s2*(1.f/96.f) - mean*mean;
    float rsd = rsqrtf(var + 1e-5f);
    float* orow = out + r*96;
    #pragma unroll
    for (int i = 0; i < 6; ++i){
      int c = l + 16*i;
      orow[c] = (vals[i]-mean)*rsd*g[c] + b[c];
    }
  }
}

template<int K, int C, int LDW, bool GELU, bool HASB, bool RES, bool ACC>
__device__ __forceinline__ void mm16(const float* __restrict__ inb, int S,
                                     const float* __restrict__ Wg, const float* __restrict__ bg,
                                     float* __restrict__ outb, int So,
                                     const float* __restrict__ residb, int t)
{
  constexpr int C4 = C/4;
  const float4* __restrict__ W4 = (const float4*)Wg;
  for (int gi = t; gi < C4*16; gi += NTB){
    const int r = gi & 15, c4 = gi >> 4;
    const float2* x = (const float2*)(inb + r*S);
    float4 a = HASB ? ((const float4*)bg)[c4] : make_float4(0.f,0.f,0.f,0.f);
    #pragma unroll 8
    for (int k2 = 0; k2 < K/2; ++k2){
      float2 xv = x[k2];
      fma4(a, xv.x, W4[(2*k2)*(LDW/4) + c4]);
      fma4(a, xv.y, W4[(2*k2+1)*(LDW/4) + c4]);
    }
    if (GELU){ a.x=gelu_f(a.x); a.y=gelu_f(a.y); a.z=gelu_f(a.z); a.w=gelu_f(a.w); }
    if (RES){
      float4 rr = *(const float4*)(residb + r*100 + 4*c4);
      a.x += rr.x; a.y += rr.y; a.z += rr.z; a.w += rr.w;
    }
    float* o = outb + r*So + 4*c4;
    if (ACC){
      float4 ov = *(const float4*)o;
      a.x += ov.x; a.y += ov.y; a.z += ov.z; a.w += ov.w;
    }
    *(float4*)o = a;
  }
}

template<int K, int C, int LDW, bool GELU, bool HASB, bool RES>
__device__ __forceinline__ void mmpx(const float* __restrict__ inb, int S,
                                     const float* __restrict__ Wg, const float* __restrict__ bg,
                                     float* __restrict__ outb, int So,
                                     const float* __restrict__ residb, int Sr, int t)
{
  for (int gi = t; gi < 4*C; gi += NTB){
    const int kq = gi & 3, c = gi >> 2;
    const int k0 = kq*(K/4);
    float a0 = 0.f, a1 = 0.f;
    #pragma unroll 8
    for (int kk = 0; kk < K/4; ++kk){
      const float w = Wg[(k0+kk)*LDW + c];
      a0 = fmaf(inb[k0+kk],     w, a0);
      a1 = fmaf(inb[S + k0+kk], w, a1);
    }
    a0 += __shfl_xor(a0, 1); a1 += __shfl_xor(a1, 1);
    a0 += __shfl_xor(a0, 2); a1 += __shfl_xor(a1, 2);
    if (kq == 0){
      if (HASB){ const float b = bg[c]; a0 += b; a1 += b; }
      if (GELU){ a0 = gelu_f(a0); a1 = gelu_f(a1); }
      if (RES){ a0 += residb[c]; a1 += residb[Sr + c]; }
      outb[c] = a0; outb[So + c] = a1;
    }
  }
}

__global__ __launch_bounds__(NTB)
void mva_phaseB(BParams P)
{
  __shared__ __align__(16) float smem[SMTOT];
  const int t = threadIdx.x;
  const int bpx0 = blockIdx.x*2;

  for (int u = t; u < 1024; u += NTB){
    const int r = u >> 6, k = u & 63;
    const int pl = r >> 3, v = r & 7;
    float val = (k < 3) ? P.rgb[((bpx0+pl)*8 + v)*3 + k]
                        : P.fm[(bpx0+pl)*61 + (k-3)];
    smem[XINB + r*100 + k] = val;
  }
  for (int u = t; u < 512; u += NTB){
    const int r = u >> 5, c = u & 31;
    smem[XINB + r*100 + 64 + c] = P.feat[(size_t)blockIdx.x*512 + r*32 + c];
  }
  if (t < 16){
    float pe = P.proj_err[(bpx0 + (t>>3))*8 + (t&7)];
    float wraw = fmaxf(-log10f(fabsf(pe) + 1e-6f), 0.f);
    float s = wraw;
    s += __shfl_xor(s, 1); s += __shfl_xor(s, 2); s += __shfl_xor(s, 4);
    smem[WGTB + t] = wraw / (s + 1e-6f);
  }
  __syncthreads();

  // tv1
  ln16(smem+XINB, smem+XLN, P.tv1_ln_g, P.tv1_ln_b, t);
  __syncthreads();
  mm16<96,32,32,false,false,false,false>(smem+XLN, 100, P.tv1_w, nullptr, smem+VB, 36, nullptr, t);
  __syncthreads();
  if (t < 64){
    const int pl = t >> 5, c = t & 31;
    const float* wn = smem + WGTB + pl*8;
    float m = 0.f;
    #pragma unroll
    for (int v = 0; v < 8; ++v) m += wn[v]*smem[VB + (pl*8+v)*36 + c];
    float vv = 0.f;
    #pragma unroll
    for (int v = 0; v < 8; ++v){ float d = smem[VB + (pl*8+v)*36 + c] - m; vv += wn[v]*d*d; }
    smem[MEANB + pl*32 + c] = m;
    smem[VARB  + pl*32 + c] = vv;
  }
  __syncthreads();
  for (int u = t; u < 1536; u += NTB){
    const int c = u >> 4, r = u & 15;
    const int pl = r >> 3;
    float val = (c < 32) ? smem[VB + r*36 + c]
              : (c < 64) ? smem[MEANB + pl*32 + (c-32)]
                         : smem[VARB + pl*32 + (c-64)];
    smem[XLN + r*100 + c] = val;
  }
  __syncthreads();
  mm16<96,96,96,false,true,true,false>(smem+XLN, 100, P.to1_w, P.to1_b, smem+XCUR, 100, smem+XINB, t);
  __syncthreads();

  // n1
  ln16(smem+XCUR, smem+XLN, P.n1_ln_g, P.n1_ln_b, t);
  __syncthreads();
  mm16<96,128,256,true,true,false,false>(smem+XLN, 100, P.n1_w1, P.n1_b1, smem+HID, 132, nullptr, t);
  __syncthreads();
  mm16<128,96,96,false,true,true,false>(smem+HID, 132, P.n1_w2, P.n1_b2, smem+XCUR, 100, smem+XINB, t);
  __syncthreads();
  mm16<96,128,256,true,true,false,false>(smem+XLN, 100, P.n1_w1 + 128, P.n1_b1 + 128, smem+HID, 132, nullptr, t);
  __syncthreads();
  mm16<128,96,96,false,false,false,true>(smem+HID, 132, P.n1_w2 + 128*96, nullptr, smem+XCUR, 100, nullptr, t);
  __syncthreads();

  // tv2 + stats
  ln16(smem+XCUR, smem+XLN, P.tv2_ln_g, P.tv2_ln_b, t);
  __syncthreads();
  mm16<96,32,32,false,false,false,false>(smem+XLN, 100, P.tv2_w, nullptr, smem+VB, 36, nullptr, t);
  __syncthreads();
  if (t < 64){
    const int pl = t >> 5, c = t & 31;
    const float* wn = smem + WGTB + pl*8;
    float m = 0.f;
    #pragma unroll
    for (int v = 0; v < 8; ++v) m += wn[v]*smem[VB + (pl*8+v)*36 + c];
    float vv = 0.f;
    #pragma unroll
    for (int v = 0; v < 8; ++v){ float d = smem[VB + (pl*8+v)*36 + c] - m; vv += wn[v]*d*d; }
    smem[MEANB + pl*32 + c] = m;
    smem[VARB  + pl*32 + c] = vv;
  }
  __syncthreads();
  if (t < 192){
    const int pl = t / 96, k = t - pl*96;
    float val = (k < 32) ? smem[VB + (pl*8)*36 + k]
              : (k < 64) ? smem[MEANB + pl*32 + (k-32)]
                         : smem[VARB + pl*32 + (k-64)];
    smem[XSLNB + pl*96 + k] = val;
  }
  __syncthreads();
  mmpx<96,96,96,false,true,true>(smem+XSLNB, 96, P.to2_w, P.to2_b, smem+XSB, 96, smem+XINB, 800, t);
  __syncthreads();

  // n2
  lnP(smem+XSB, smem+XSLNB, P.n2_ln_g, P.n2_ln_b, t);
  __syncthreads();
  mmpx<96,256,256,true,true,false>(smem+XSLNB, 96, P.n2_w1, P.n2_b1, smem+HID, 260, nullptr, 0, t);
  __syncthreads();
  mmpx<256,96,96,false,true,true>(smem+HID, 260, P.n2_w2, P.n2_b2, smem+XSB, 96, smem+XINB, 800, t);
  __syncthreads();

  // brdf
  lnP(smem+XSB, smem+XSLNB, P.brdf_ln_g, P.brdf_ln_b, t);
  __syncthreads();
  mmpx<96,128,128,true,true,false>(smem+XSLNB, 96, P.brdf_w1, P.brdf_b1, smem+HID, 260, nullptr, 0, t);
  __syncthreads();
  mmpx<128,128,128,false,true,false>(smem+HID, 260, P.brdf_w2, P.brdf_b2,
                                     P.out + (size_t)bpx0*128, 128, nullptr, 0, t);
}

extern "C" void kernel_launch(void* const* d_in, const int* in_sizes, int n_in,
                              void* d_out, int out_size, void* d_ws, size_t ws_size,
                              hipStream_t stream)
{
  (void)in_sizes; (void)n_in; (void)ws_size; (void)out_size;
  int i = 0;
  const float* rgb      = (const float*)d_in[i++];
  const float* fm       = (const float*)d_in[i++];
  const float* view_dir = (const float*)d_in[i++];
  const float* proj_err = (const float*)d_in[i++];
  const float* normal   = (const float*)d_in[i++];
  const float* DL       = (const float*)d_in[i++];

  AParams A;
  A.view_dir = view_dir; A.normal = normal; A.DL = DL;
  A.ln_g = (const float*)d_in[i++]; A.ln_b = (const float*)d_in[i++];
  A.w1 = (const float*)d_in[i++]; A.b1 = (const float*)d_in[i++];
  A.w2 = (const float*)d_in[i++]; A.b2 = (const float*)d_in[i++];
  A.w3 = (const float*)d_in[i++]; A.b3 = (const float*)d_in[i++];
  A.w4 = (const float*)d_in[i++]; A.b4 = (const float*)d_in[i++];
  A.feat = (float*)d_ws;

  BParams B;
  B.rgb = rgb; B.fm = fm; B.proj_err = proj_err; B.feat = (const float*)d_ws;
  B.tv1_ln_g = (const float*)d_in[i++]; B.tv1_ln_b = (const float*)d_in[i++];
  B.tv1_w = (const float*)d_in[i++];
  B.to1_w = (const float*)d_in[i++]; B.to1_b = (const float*)d_in[i++];
  B.n1_ln_g = (const float*)d_in[i++]; B.n1_ln_b = (const float*)d_in[i++];
  B.n1_w1 = (const float*)d_in[i++]; B.n1_b1 = (const float*)d_in[i++];
  B.n1_w2 = (const float*)d_in[i++]; B.n1_b2 = (const float*)d_in[i++];
  B.tv2_ln_g = (const float*)d_in[i++]; B.tv2_ln_b = (const float*)d_in[i++];
  B.tv2_w = (const float*)d_in[i++];
  B.to2_w = (const float*)d_in[i++]; B.to2_b = (const float*)d_in[i++];
  B.n2_ln_g = (const float*)d_in[i++]; B.n2_ln_b = (const float*)d_in[i++];
  B.n2_w1 = (const float*)d_in[i++]; B.n2_b1 = (const float*)d_in[i++];
  B.n2_w2 = (const float*)d_in[i++]; B.n2_b2 = (const float*)d_in[i++];
  B.brdf_ln_g = (const float*)d_in[i++]; B.brdf_ln_b = (const float*)d_in[i++];
  B.brdf_w1 = (const float*)d_in[i++]; B.brdf_b1 = (const float*)d_in[i++];
  B.brdf_w2 = (const float*)d_in[i++]; B.brdf_b2 = (const float*)d_in[i++];
  B.out = (float*)d_out;

  mva_phaseA<<<dim3(NBA), dim3(NTA), 0, stream>>>(A);
  mva_phaseB<<<dim3(NBB), dim3(NTB), 0, stream>>>(B);
}